// Round 13
// baseline (264.825 us; speedup 1.0000x reference)
//
#include <hip/hip_runtime.h>
#include <math.h>

#define N_ROWS 262144
#define DIM 64
#define K_CODES 1024
#define NT 64                 // code tiles of 16
#define ROWS_PER_BLOCK 128
#define EPSF 1e-12f

typedef _Float16 f16x8 __attribute__((ext_vector_type(8)));
typedef float f32x4 __attribute__((ext_vector_type(4)));

// ws layout (floats):
//   wn      : [0, 65536)         normalized codebook fp32 (gather/epilogue)
//   msw     : [65536, 66560)     -0.5 * sum(wn^2) per code
//   partial : [66560, 68608)     per-block loss partials (2048)
//   wf      : halves after that  codebook hi/lo f16, 16x16x32 B-fragment order
//             per 16-code tile t: 2048 halves:
//               [0,512)=hi s0  [512,1024)=hi s1  [1024,1536)=lo s0  [1536,2048)=lo s1
//             within each 512: lane(= g*16 + code%16)*8 + i,  k-dim = s*32+g*8+i

__global__ __launch_bounds__(64) void prep_codebook(
    const float* __restrict__ w, float* __restrict__ wn,
    float* __restrict__ msw, _Float16* __restrict__ wf)
{
    int k = blockIdx.x;
    int d = threadIdx.x;
    float v = w[k * DIM + d];
    float sq = v * v;
    #pragma unroll
    for (int off = 32; off; off >>= 1) sq += __shfl_xor(sq, off, 64);
    float n = fmaxf(sqrtf(sq), EPSF);
    float o = v / n;
    wn[k * DIM + d] = o;
    float s2 = o * o;
    #pragma unroll
    for (int off = 32; off; off >>= 1) s2 += __shfl_xor(s2, off, 64);
    if (d == 0) msw[k] = -0.5f * s2;

    _Float16 hi = (_Float16)o;
    _Float16 lo = (_Float16)(o - (float)hi);
    // B fragment for 16x16x32: lane = g*16 + n holds k-dims s*32 + g*8 + i
    int t = k >> 4, nn = k & 15, s = d >> 5, g = (d >> 3) & 3, i = d & 7;
    size_t base = (size_t)t * 2048 + (size_t)s * 512 + (size_t)(g * 16 + nn) * 8 + i;
    wf[base] = hi;            // h = 0
    wf[base + 1024] = lo;     // h = 1
}

#define MFMA_(A, B, C) C = __builtin_amdgcn_mfma_f32_16x16x32_f16(A, B, C, 0, 0, 0)

__global__ __launch_bounds__(256, 6) void vq_main_kernel(
    const float* __restrict__ x,
    const float* __restrict__ wn,
    const float* __restrict__ msw,
    const _Float16* __restrict__ wf,
    float* __restrict__ out_q,
    float* __restrict__ out_idx,
    float* __restrict__ partial)
{
    __shared__ _Float16 bbuf[2][2048];        // double-buffered 4 KB code tiles
    __shared__ float msw_lds[K_CODES];
    __shared__ int idx_lds[ROWS_PER_BLOCK];
    __shared__ float inv_lds[ROWS_PER_BLOCK];
    __shared__ float red[4];

    const int tid = threadIdx.x;              // 0..255 (4 waves)
    const int wv = tid >> 6;
    const int lane = tid & 63;
    const int nidx = lane & 15;       // code-within-tile / x-row-within-rowtile
    const int g = lane >> 4;          // k-group
    const int block_row0 = blockIdx.x * ROWS_PER_BLOCK;

    // ---- prologue: 32 rows/wave (2 row-tiles of 16), normalize, hi/lo A-frags ----
    // A for 16x16x32: lane = g*16+m holds A[m][k = g*8+i] (+s*32 per kstep)
    f16x8 ah[2][2], al[2][2];
    #pragma unroll
    for (int rt = 0; rt < 2; ++rt) {
        const int arow = block_row0 + wv * 32 + rt * 16 + nidx;
        const float* xrow = x + (size_t)arow * DIM + g * 8;
        float xv[2][8];
        #pragma unroll
        for (int s = 0; s < 2; ++s) {
            float4 q0 = *(const float4*)(xrow + s * 32);
            float4 q1 = *(const float4*)(xrow + s * 32 + 4);
            xv[s][0] = q0.x; xv[s][1] = q0.y; xv[s][2] = q0.z; xv[s][3] = q0.w;
            xv[s][4] = q1.x; xv[s][5] = q1.y; xv[s][6] = q1.z; xv[s][7] = q1.w;
        }
        float ss = 0.f;
        #pragma unroll
        for (int s = 0; s < 2; ++s)
            #pragma unroll
            for (int i = 0; i < 8; ++i) ss += xv[s][i] * xv[s][i];
        ss += __shfl_xor(ss, 16, 64);  // sum across the 4 k-groups of this row
        ss += __shfl_xor(ss, 32, 64);
        float nrm = fmaxf(sqrtf(ss), EPSF);
        float inv = 1.0f / nrm;
        if (g == 0) inv_lds[wv * 32 + rt * 16 + nidx] = inv;
        #pragma unroll
        for (int s = 0; s < 2; ++s)
            #pragma unroll
            for (int i = 0; i < 8; ++i) {
                float v = xv[s][i] * inv;
                _Float16 hi = (_Float16)v;
                ah[rt][s][i] = hi;
                al[rt][s][i] = (_Float16)(v - (float)hi);
            }
    }

    // ---- stage msw into LDS, conflict-free 16B/thread ----
    *(float4*)&msw_lds[tid * 4] = *(const float4*)(msw + tid * 4);

    // ---- stage tile 0 into bbuf[0]; prefetch tile 1 into regs ----
    const _Float16* gsrc = wf + (size_t)tid * 8;   // 16B per thread per tile
    {
        f16x8 s0 = *(const f16x8*)(gsrc);
        *(f16x8*)&bbuf[0][tid * 8] = s0;
    }
    f16x8 stg = *(const f16x8*)(gsrc + 2048);
    gsrc += 2 * 2048;                               // next load target: tile 2
    __syncthreads();

    float best[2][4];
    int bt[2][4];
    #pragma unroll
    for (int rt = 0; rt < 2; ++rt)
        #pragma unroll
        for (int r = 0; r < 4; ++r) { best[rt][r] = -3.4e38f; bt[rt][r] = 0; }

    // ---- main loop: 64 tiles, LDS double-buffer ----
    // Sync discipline (T4): only lgkmcnt(0) is drained at the barrier (for the
    // ds_write's cross-wave visibility). The global prefetch of tile t+2 stays
    // in flight across the barrier; its vmcnt wait lands at next iteration's
    // ds_write of stg — a full tile body of latency cover.
    for (int t = 0; t < NT; ++t) {
        const int cur = t & 1;
        const _Float16* bp = &bbuf[cur][lane * 8];
        f16x8 b0 = *(const f16x8*)(bp);
        f16x8 b1 = *(const f16x8*)(bp + 512);
        f16x8 b2 = *(const f16x8*)(bp + 1024);
        f16x8 b3 = *(const f16x8*)(bp + 1536);
        float mval = msw_lds[t * 16 + nidx];

        f32x4 acc0 = {mval, mval, mval, mval};
        f32x4 acc1 = acc0;
        __builtin_amdgcn_s_setprio(1);
        // 12 MFMA: two independent depth-6 chains (row-tile 0 / row-tile 1)
        MFMA_(ah[0][0], b0, acc0); MFMA_(ah[1][0], b0, acc1);
        MFMA_(ah[0][1], b1, acc0); MFMA_(ah[1][1], b1, acc1);
        MFMA_(al[0][0], b0, acc0); MFMA_(al[1][0], b0, acc1);
        MFMA_(al[0][1], b1, acc0); MFMA_(al[1][1], b1, acc1);
        MFMA_(ah[0][0], b2, acc0); MFMA_(ah[1][0], b2, acc1);
        MFMA_(ah[0][1], b3, acc0); MFMA_(ah[1][1], b3, acc1);
        __builtin_amdgcn_s_setprio(0);

        // write staged tile t+1 into the other buffer, then issue the load
        // for tile t+2 (issue-early / write-late)
        if (t + 1 < NT) {
            *(f16x8*)&bbuf[cur ^ 1][tid * 8] = stg;
            if (t + 2 < NT) {
                stg = *(const f16x8*)(gsrc);
                gsrc += 2048;
            }
        }

        // compare (strict > keeps earliest tile => first-argmin tie semantics);
        // register-only, fills the lgkm drain window
        #pragma unroll
        for (int r = 0; r < 4; ++r) {
            if (acc0[r] > best[0][r]) { best[0][r] = acc0[r]; bt[0][r] = t; }
            if (acc1[r] > best[1][r]) { best[1][r] = acc1[r]; bt[1][r] = t; }
        }

        if (t + 1 < NT) {
            asm volatile("s_waitcnt lgkmcnt(0)" ::: "memory");
            __builtin_amdgcn_s_barrier();
        }
    }

    // ---- argmax reduce across the 16 lanes holding each row ----
    // C 16x16: col = lane&15 (code), row = (lane>>4)*4 + r
    #pragma unroll
    for (int rt = 0; rt < 2; ++rt)
        #pragma unroll
        for (int r = 0; r < 4; ++r) {
            float b = best[rt][r];
            int bi = bt[rt][r] * 16 + nidx;
            #pragma unroll
            for (int off = 1; off <= 8; off <<= 1) {
                float ob = __shfl_xor(b, off, 64);
                int oi = __shfl_xor(bi, off, 64);
                if (ob > b || (ob == b && oi < bi)) { b = ob; bi = oi; }
            }
            if (nidx == 0)
                idx_lds[wv * 32 + rt * 16 + g * 4 + r] = bi;
        }
    __syncthreads();

    // ---- epilogue: gather fp32 codebook row, write out, loss partial ----
    const int lr = tid >> 1;
    const int grow = block_row0 + lr;
    const int d0 = (tid & 1) * 32;
    const int ci = idx_lds[lr];
    const float invn = inv_lds[lr];
    const float4* xp = (const float4*)(x + (size_t)grow * DIM + d0);
    const float4* qp = (const float4*)(wn + (size_t)ci * DIM + d0);
    float4* op = (float4*)(out_q + (size_t)grow * DIM + d0);
    float ls = 0.f;
    #pragma unroll
    for (int i = 0; i < 8; ++i) {
        float4 qv = qp[i];
        float4 xv4 = xp[i];
        float e0 = qv.x - xv4.x * invn;
        float e1 = qv.y - xv4.y * invn;
        float e2 = qv.z - xv4.z * invn;
        float e3 = qv.w - xv4.w * invn;
        ls += e0 * e0 + e1 * e1 + e2 * e2 + e3 * e3;
        op[i] = qv;
    }
    if (!(tid & 1)) out_idx[grow] = (float)ci;

    float s = ls;
    #pragma unroll
    for (int off = 32; off; off >>= 1) s += __shfl_xor(s, off, 64);
    if (lane == 0) red[wv] = s;
    __syncthreads();
    if (tid == 0) partial[blockIdx.x] = (red[0] + red[1]) + (red[2] + red[3]);
}

__global__ __launch_bounds__(256) void finalize_kernel(
    const float* __restrict__ partial, float* __restrict__ loss_out)
{
    __shared__ float red[4];
    int t = threadIdx.x;
    float s = 0.f;
    #pragma unroll
    for (int i = 0; i < 8; ++i) s += partial[t * 8 + i];  // fixed order
    #pragma unroll
    for (int off = 32; off; off >>= 1) s += __shfl_xor(s, off, 64);
    if ((t & 63) == 0) red[t >> 6] = s;
    __syncthreads();
    if (t == 0)
        *loss_out = 1.25f * (((red[0] + red[1]) + (red[2] + red[3]))
                             / (float)((size_t)N_ROWS * DIM));
}

extern "C" void kernel_launch(void* const* d_in, const int* in_sizes, int n_in,
                              void* d_out, int out_size, void* d_ws, size_t ws_size,
                              hipStream_t stream) {
    const float* x = (const float*)d_in[0];   // [N, D]
    const float* w = (const float*)d_in[1];   // [K, D]
    float* out = (float*)d_out;
    float* ws = (float*)d_ws;

    float* wn      = ws;                                   // 65536 floats
    float* msw     = wn + (size_t)K_CODES * DIM;           // 1024 floats
    float* partial = msw + K_CODES;                        // 2048 floats
    _Float16* wf   = (_Float16*)(partial + 2048);          // 64*2048 halves

    float* out_q    = out;                                 // [N*D]
    float* out_loss = out + (size_t)N_ROWS * DIM;          // [1]
    float* out_idx  = out_loss + 1;                        // [N]

    prep_codebook<<<K_CODES, 64, 0, stream>>>(w, wn, msw, wf);
    vq_main_kernel<<<N_ROWS / ROWS_PER_BLOCK, 256, 0, stream>>>(
        x, wn, msw, wf, out_q, out_idx, partial);
    finalize_kernel<<<1, 256, 0, stream>>>(partial, out_loss);
}

// Round 14
// 182.327 us; speedup vs baseline: 1.4525x; 1.4525x over previous
//
#include <hip/hip_runtime.h>
#include <math.h>

#define N_ROWS 262144
#define DIM 64
#define K_CODES 1024
#define NT 64                 // code tiles of 16
#define ROWS_PER_BLOCK 128
#define EPSF 1e-12f

typedef _Float16 f16x8 __attribute__((ext_vector_type(8)));
typedef float f32x4 __attribute__((ext_vector_type(4)));

// ws layout (floats):
//   wn      : [0, 65536)         normalized codebook fp32 (gather/epilogue)
//   msw     : [65536, 66560)     -0.5 * sum(wn^2) per code
//   partial : [66560, 68608)     per-block loss partials (2048)
//   wf      : halves after that  codebook hi/lo f16, 16x16x32 B-fragment order
//             per 16-code tile t: 2048 halves:
//               [0,512)=hi s0  [512,1024)=hi s1  [1024,1536)=lo s0  [1536,2048)=lo s1
//             within each 512: lane(= g*16 + code%16)*8 + i,  k-dim = s*32+g*8+i
//             +2 uninitialized guard tiles (prefetch targets for t=64,65; never consumed)

__global__ __launch_bounds__(64) void prep_codebook(
    const float* __restrict__ w, float* __restrict__ wn,
    float* __restrict__ msw, _Float16* __restrict__ wf)
{
    int k = blockIdx.x;
    int d = threadIdx.x;
    float v = w[k * DIM + d];
    float sq = v * v;
    #pragma unroll
    for (int off = 32; off; off >>= 1) sq += __shfl_xor(sq, off, 64);
    float n = fmaxf(sqrtf(sq), EPSF);
    float o = v / n;
    wn[k * DIM + d] = o;
    float s2 = o * o;
    #pragma unroll
    for (int off = 32; off; off >>= 1) s2 += __shfl_xor(s2, off, 64);
    if (d == 0) msw[k] = -0.5f * s2;

    _Float16 hi = (_Float16)o;
    _Float16 lo = (_Float16)(o - (float)hi);
    // B fragment for 16x16x32: lane = g*16 + n holds k-dims s*32 + g*8 + i
    int t = k >> 4, nn = k & 15, s = d >> 5, g = (d >> 3) & 3, i = d & 7;
    size_t base = (size_t)t * 2048 + (size_t)s * 512 + (size_t)(g * 16 + nn) * 8 + i;
    wf[base] = hi;            // h = 0
    wf[base + 1024] = lo;     // h = 1
}

#define MFMA_(A, B, C) C = __builtin_amdgcn_mfma_f32_16x16x32_f16(A, B, C, 0, 0, 0)

// One tile body. Invariant at entry: bbuf[CUR] holds tile T, STGC holds tile
// T+1 (its load has been in flight for a full body). Steps: write T+1 into
// bbuf[CUR^1] (vmcnt wait ~free), issue load of T+2 into STGN (in flight
// across this body's MFMAs => cheap drain at the barrier), ds_read + MFMA +
// compare, barrier.
#define BODY(T, CUR, STGC, STGN)                                              \
  {                                                                           \
    *(f16x8*)&bbuf[(CUR) ^ 1][tid * 8] = STGC;                                \
    STGN = *(const f16x8*)(gnext);                                            \
    gnext += 2048;                                                            \
    const _Float16* bp = &bbuf[CUR][lane * 8];                                \
    f16x8 b0 = *(const f16x8*)(bp);                                           \
    f16x8 b1 = *(const f16x8*)(bp + 512);                                     \
    f16x8 b2 = *(const f16x8*)(bp + 1024);                                    \
    f16x8 b3 = *(const f16x8*)(bp + 1536);                                    \
    float mval = msw_lds[(T) * 16 + nidx];                                    \
    f32x4 acc0 = {mval, mval, mval, mval};                                    \
    f32x4 acc1 = acc0;                                                        \
    __builtin_amdgcn_s_setprio(1);                                            \
    MFMA_(ah[0][0], b0, acc0); MFMA_(ah[1][0], b0, acc1);                     \
    MFMA_(ah[0][1], b1, acc0); MFMA_(ah[1][1], b1, acc1);                     \
    MFMA_(al[0][0], b0, acc0); MFMA_(al[1][0], b0, acc1);                     \
    MFMA_(al[0][1], b1, acc0); MFMA_(al[1][1], b1, acc1);                     \
    MFMA_(ah[0][0], b2, acc0); MFMA_(ah[1][0], b2, acc1);                     \
    MFMA_(ah[0][1], b3, acc0); MFMA_(ah[1][1], b3, acc1);                     \
    __builtin_amdgcn_s_setprio(0);                                            \
    _Pragma("unroll")                                                         \
    for (int r = 0; r < 4; ++r) {                                             \
      if (acc0[r] > best[0][r]) { best[0][r] = acc0[r]; bt[0][r] = (T); }     \
      if (acc1[r] > best[1][r]) { best[1][r] = acc1[r]; bt[1][r] = (T); }     \
    }                                                                         \
    __syncthreads();                                                          \
  }

__global__ __launch_bounds__(256, 6) void vq_main_kernel(
    const float* __restrict__ x,
    const float* __restrict__ wn,
    const float* __restrict__ msw,
    const _Float16* __restrict__ wf,
    float* __restrict__ out_q,
    float* __restrict__ out_idx,
    float* __restrict__ partial)
{
    __shared__ _Float16 bbuf[2][2048];        // double-buffered 4 KB code tiles
    __shared__ float msw_lds[K_CODES];
    __shared__ int idx_lds[ROWS_PER_BLOCK];
    __shared__ float inv_lds[ROWS_PER_BLOCK];
    __shared__ float red[4];

    const int tid = threadIdx.x;              // 0..255 (4 waves)
    const int wv = tid >> 6;
    const int lane = tid & 63;
    const int nidx = lane & 15;       // code-within-tile / x-row-within-rowtile
    const int g = lane >> 4;          // k-group
    const int block_row0 = blockIdx.x * ROWS_PER_BLOCK;

    // ---- prologue: 32 rows/wave (2 row-tiles of 16), normalize, hi/lo A-frags ----
    // A for 16x16x32: lane = g*16+m holds A[m][k = g*8+i] (+s*32 per kstep)
    f16x8 ah[2][2], al[2][2];
    #pragma unroll
    for (int rt = 0; rt < 2; ++rt) {
        const int arow = block_row0 + wv * 32 + rt * 16 + nidx;
        const float* xrow = x + (size_t)arow * DIM + g * 8;
        float xv[2][8];
        #pragma unroll
        for (int s = 0; s < 2; ++s) {
            float4 q0 = *(const float4*)(xrow + s * 32);
            float4 q1 = *(const float4*)(xrow + s * 32 + 4);
            xv[s][0] = q0.x; xv[s][1] = q0.y; xv[s][2] = q0.z; xv[s][3] = q0.w;
            xv[s][4] = q1.x; xv[s][5] = q1.y; xv[s][6] = q1.z; xv[s][7] = q1.w;
        }
        float ss = 0.f;
        #pragma unroll
        for (int s = 0; s < 2; ++s)
            #pragma unroll
            for (int i = 0; i < 8; ++i) ss += xv[s][i] * xv[s][i];
        ss += __shfl_xor(ss, 16, 64);  // sum across the 4 k-groups of this row
        ss += __shfl_xor(ss, 32, 64);
        float nrm = fmaxf(sqrtf(ss), EPSF);
        float inv = 1.0f / nrm;
        if (g == 0) inv_lds[wv * 32 + rt * 16 + nidx] = inv;
        #pragma unroll
        for (int s = 0; s < 2; ++s)
            #pragma unroll
            for (int i = 0; i < 8; ++i) {
                float v = xv[s][i] * inv;
                _Float16 hi = (_Float16)v;
                ah[rt][s][i] = hi;
                al[rt][s][i] = (_Float16)(v - (float)hi);
            }
    }

    // ---- stage msw into LDS, conflict-free 16B/thread ----
    *(float4*)&msw_lds[tid * 4] = *(const float4*)(msw + tid * 4);

    // ---- stage tile 0 into bbuf[0]; load tile 1 into stgA ----
    const _Float16* gsrc = wf + (size_t)tid * 8;   // 16B per thread per tile
    {
        f16x8 s0 = *(const f16x8*)(gsrc);
        *(f16x8*)&bbuf[0][tid * 8] = s0;
    }
    f16x8 stgA = *(const f16x8*)(gsrc + 2048);
    f16x8 stgB;
    const _Float16* gnext = gsrc + 2 * 2048;       // next load: tile 2
    __syncthreads();

    float best[2][4];
    int bt[2][4];
    #pragma unroll
    for (int rt = 0; rt < 2; ++rt)
        #pragma unroll
        for (int r = 0; r < 4; ++r) { best[rt][r] = -3.4e38f; bt[rt][r] = 0; }

    // ---- main loop: 64 tiles, LDS double-buffer, issue-early prefetch ----
    for (int it = 0; it < NT; it += 2) {
        BODY(it,     0, stgA, stgB)
        BODY(it + 1, 1, stgB, stgA)
    }

    // ---- argmax reduce across the 16 lanes holding each row ----
    // C 16x16: col = lane&15 (code), row = (lane>>4)*4 + r
    #pragma unroll
    for (int rt = 0; rt < 2; ++rt)
        #pragma unroll
        for (int r = 0; r < 4; ++r) {
            float b = best[rt][r];
            int bi = bt[rt][r] * 16 + nidx;
            #pragma unroll
            for (int off = 1; off <= 8; off <<= 1) {
                float ob = __shfl_xor(b, off, 64);
                int oi = __shfl_xor(bi, off, 64);
                if (ob > b || (ob == b && oi < bi)) { b = ob; bi = oi; }
            }
            if (nidx == 0)
                idx_lds[wv * 32 + rt * 16 + g * 4 + r] = bi;
        }
    __syncthreads();

    // ---- epilogue: gather fp32 codebook row, write out, loss partial ----
    const int lr = tid >> 1;
    const int grow = block_row0 + lr;
    const int d0 = (tid & 1) * 32;
    const int ci = idx_lds[lr];
    const float invn = inv_lds[lr];
    const float4* xp = (const float4*)(x + (size_t)grow * DIM + d0);
    const float4* qp = (const float4*)(wn + (size_t)ci * DIM + d0);
    float4* op = (float4*)(out_q + (size_t)grow * DIM + d0);
    float ls = 0.f;
    #pragma unroll
    for (int i = 0; i < 8; ++i) {
        float4 qv = qp[i];
        float4 xv4 = xp[i];
        float e0 = qv.x - xv4.x * invn;
        float e1 = qv.y - xv4.y * invn;
        float e2 = qv.z - xv4.z * invn;
        float e3 = qv.w - xv4.w * invn;
        ls += e0 * e0 + e1 * e1 + e2 * e2 + e3 * e3;
        op[i] = qv;
    }
    if (!(tid & 1)) out_idx[grow] = (float)ci;

    float s = ls;
    #pragma unroll
    for (int off = 32; off; off >>= 1) s += __shfl_xor(s, off, 64);
    if (lane == 0) red[wv] = s;
    __syncthreads();
    if (tid == 0) partial[blockIdx.x] = (red[0] + red[1]) + (red[2] + red[3]);
}

__global__ __launch_bounds__(256) void finalize_kernel(
    const float* __restrict__ partial, float* __restrict__ loss_out)
{
    __shared__ float red[4];
    int t = threadIdx.x;
    float s = 0.f;
    #pragma unroll
    for (int i = 0; i < 8; ++i) s += partial[t * 8 + i];  // fixed order
    #pragma unroll
    for (int off = 32; off; off >>= 1) s += __shfl_xor(s, off, 64);
    if ((t & 63) == 0) red[t >> 6] = s;
    __syncthreads();
    if (t == 0)
        *loss_out = 1.25f * (((red[0] + red[1]) + (red[2] + red[3]))
                             / (float)((size_t)N_ROWS * DIM));
}

extern "C" void kernel_launch(void* const* d_in, const int* in_sizes, int n_in,
                              void* d_out, int out_size, void* d_ws, size_t ws_size,
                              hipStream_t stream) {
    const float* x = (const float*)d_in[0];   // [N, D]
    const float* w = (const float*)d_in[1];   // [K, D]
    float* out = (float*)d_out;
    float* ws = (float*)d_ws;

    float* wn      = ws;                                   // 65536 floats
    float* msw     = wn + (size_t)K_CODES * DIM;           // 1024 floats
    float* partial = msw + K_CODES;                        // 2048 floats
    _Float16* wf   = (_Float16*)(partial + 2048);          // 66*2048 halves (incl. 2 guard)

    float* out_q    = out;                                 // [N*D]
    float* out_loss = out + (size_t)N_ROWS * DIM;          // [1]
    float* out_idx  = out_loss + 1;                        // [N]

    prep_codebook<<<K_CODES, 64, 0, stream>>>(w, wn, msw, wf);
    vq_main_kernel<<<N_ROWS / ROWS_PER_BLOCK, 256, 0, stream>>>(
        x, wn, msw, wf, out_q, out_idx, partial);
    finalize_kernel<<<1, 256, 0, stream>>>(partial, out_loss);
}

// Round 15
// 131.955 us; speedup vs baseline: 2.0069x; 1.3817x over previous
//
#include <hip/hip_runtime.h>
#include <math.h>

#define N_ROWS 262144
#define DIM 64
#define K_CODES 1024
#define NT 64                 // code tiles of 16
#define ROWS_PER_BLOCK 128
#define EPSF 1e-12f

typedef _Float16 f16x8 __attribute__((ext_vector_type(8)));
typedef float f32x4 __attribute__((ext_vector_type(4)));

// ws layout (floats):
//   wn      : [0, 65536)         normalized codebook fp32 (gather/epilogue)
//   msw     : [65536, 66560)     -0.5 * sum(wn^2) per code
//   partial : [66560, 68608)     per-block loss partials (2048)
//   wf      : halves after that  codebook hi/lo f16, 16x16x32 B-fragment order
//             per 16-code tile t: 2048 halves:
//               [0,512)=hi s0  [512,1024)=hi s1  [1024,1536)=lo s0  [1536,2048)=lo s1
//             within each 512: lane(= g*16 + code%16)*8 + i,  k-dim = s*32+g*8+i

__global__ __launch_bounds__(64) void prep_codebook(
    const float* __restrict__ w, float* __restrict__ wn,
    float* __restrict__ msw, _Float16* __restrict__ wf)
{
    int k = blockIdx.x;
    int d = threadIdx.x;
    float v = w[k * DIM + d];
    float sq = v * v;
    #pragma unroll
    for (int off = 32; off; off >>= 1) sq += __shfl_xor(sq, off, 64);
    float n = fmaxf(sqrtf(sq), EPSF);
    float o = v / n;
    wn[k * DIM + d] = o;
    float s2 = o * o;
    #pragma unroll
    for (int off = 32; off; off >>= 1) s2 += __shfl_xor(s2, off, 64);
    if (d == 0) msw[k] = -0.5f * s2;

    _Float16 hi = (_Float16)o;
    _Float16 lo = (_Float16)(o - (float)hi);
    // B fragment for 16x16x32: lane = g*16 + n holds k-dims s*32 + g*8 + i
    int t = k >> 4, nn = k & 15, s = d >> 5, g = (d >> 3) & 3, i = d & 7;
    size_t base = (size_t)t * 2048 + (size_t)s * 512 + (size_t)(g * 16 + nn) * 8 + i;
    wf[base] = hi;            // h = 0
    wf[base + 1024] = lo;     // h = 1
}

#define MFMA_(A, B, C) C = __builtin_amdgcn_mfma_f32_16x16x32_f16(A, B, C, 0, 0, 0)

__device__ __forceinline__ void load16_to_lds(const void* g, void* l) {
    __builtin_amdgcn_global_load_lds(
        (const __attribute__((address_space(1))) unsigned int*)g,
        (__attribute__((address_space(3))) unsigned int*)l,
        16, 0, 0);
}

__global__ __launch_bounds__(256, 5) void vq_main_kernel(
    const float* __restrict__ x,
    const float* __restrict__ wn,
    const float* __restrict__ msw,
    const _Float16* __restrict__ wf,
    float* __restrict__ out_q,
    float* __restrict__ out_idx,
    float* __restrict__ partial)
{
    __shared__ _Float16 bbuf[3 * 2048];       // triple-buffered 4 KB code tiles
    __shared__ float msw_lds[K_CODES];
    __shared__ int idx_lds[ROWS_PER_BLOCK];
    __shared__ float inv_lds[ROWS_PER_BLOCK];
    __shared__ float red[4];

    const int tid = threadIdx.x;              // 0..255 (4 waves)
    const int wv = tid >> 6;
    const int lane = tid & 63;
    const int nidx = lane & 15;       // code-within-tile / x-row-within-rowtile
    const int g = lane >> 4;          // k-group
    const int block_row0 = blockIdx.x * ROWS_PER_BLOCK;

    // ---- prologue: 32 rows/wave (2 row-tiles of 16), normalize, hi/lo A-frags ----
    // A for 16x16x32: lane = g*16+m holds A[m][k = g*8+i] (+s*32 per kstep)
    f16x8 ah[2][2], al[2][2];
    #pragma unroll
    for (int rt = 0; rt < 2; ++rt) {
        const int arow = block_row0 + wv * 32 + rt * 16 + nidx;
        const float* xrow = x + (size_t)arow * DIM + g * 8;
        float xv[2][8];
        #pragma unroll
        for (int s = 0; s < 2; ++s) {
            float4 q0 = *(const float4*)(xrow + s * 32);
            float4 q1 = *(const float4*)(xrow + s * 32 + 4);
            xv[s][0] = q0.x; xv[s][1] = q0.y; xv[s][2] = q0.z; xv[s][3] = q0.w;
            xv[s][4] = q1.x; xv[s][5] = q1.y; xv[s][6] = q1.z; xv[s][7] = q1.w;
        }
        float ss = 0.f;
        #pragma unroll
        for (int s = 0; s < 2; ++s)
            #pragma unroll
            for (int i = 0; i < 8; ++i) ss += xv[s][i] * xv[s][i];
        ss += __shfl_xor(ss, 16, 64);  // sum across the 4 k-groups of this row
        ss += __shfl_xor(ss, 32, 64);
        float nrm = fmaxf(sqrtf(ss), EPSF);
        float inv = 1.0f / nrm;
        if (g == 0) inv_lds[wv * 32 + rt * 16 + nidx] = inv;
        #pragma unroll
        for (int s = 0; s < 2; ++s)
            #pragma unroll
            for (int i = 0; i < 8; ++i) {
                float v = xv[s][i] * inv;
                _Float16 hi = (_Float16)v;
                ah[rt][s][i] = hi;
                al[rt][s][i] = (_Float16)(v - (float)hi);
            }
    }

    // ---- stage msw into LDS, conflict-free 16B/thread ----
    *(float4*)&msw_lds[tid * 4] = *(const float4*)(msw + tid * 4);

    // ---- issue async loads: tile 0 -> buf0, tile 1 -> buf1 (1 KB per wave) ----
    // per-lane global src; wave-uniform LDS dst (hardware: dst + lane*16)
    const _Float16* gnext = wf + (size_t)wv * 512 + (size_t)lane * 8;
    load16_to_lds(gnext,        &bbuf[wv * 512]);
    load16_to_lds(gnext + 2048, &bbuf[2048 + wv * 512]);
    gnext += 2 * 2048;                        // next issue target: tile 2
    __syncthreads();                          // drains vmcnt: tiles 0,1 resident

    float best[2][4];
    int bt[2][4];
    #pragma unroll
    for (int rt = 0; rt < 2; ++rt)
        #pragma unroll
        for (int r = 0; r < 4; ++r) { best[rt][r] = -3.4e38f; bt[rt][r] = 0; }

    // ---- main loop: 64 tiles, triple-buffered, issue-at-top prefetch ----
    // Invariant entering body t: buf[cur] = tile t (resident), buf[cur+1 mod 3]
    // = tile t+1 (in flight or resident), buf[cur+2 mod 3] = free (tile t-1,
    // reads finished before the last barrier). Issue t+2 there FIRST, so the
    // load is in flight across this body's MFMA cluster before the barrier's
    // vmcnt drain.
    int cur = 0;
    for (int t = 0; t < NT; ++t) {
        int nxt = cur - 1; if (nxt < 0) nxt = 2;    // (cur+2) mod 3
        if (t + 2 < NT) {
            load16_to_lds(gnext, &bbuf[nxt * 2048 + wv * 512]);
            gnext += 2048;
        }

        const _Float16* bp = &bbuf[cur * 2048 + lane * 8];
        f16x8 b0 = *(const f16x8*)(bp);
        f16x8 b1 = *(const f16x8*)(bp + 512);
        f16x8 b2 = *(const f16x8*)(bp + 1024);
        f16x8 b3 = *(const f16x8*)(bp + 1536);
        float mval = msw_lds[t * 16 + nidx];

        f32x4 acc0 = {mval, mval, mval, mval};
        f32x4 acc1 = acc0;
        __builtin_amdgcn_s_setprio(1);
        // 12 MFMA: two independent depth-6 chains (row-tile 0 / row-tile 1)
        MFMA_(ah[0][0], b0, acc0); MFMA_(ah[1][0], b0, acc1);
        MFMA_(ah[0][1], b1, acc0); MFMA_(ah[1][1], b1, acc1);
        MFMA_(al[0][0], b0, acc0); MFMA_(al[1][0], b0, acc1);
        MFMA_(al[0][1], b1, acc0); MFMA_(al[1][1], b1, acc1);
        MFMA_(ah[0][0], b2, acc0); MFMA_(ah[1][0], b2, acc1);
        MFMA_(ah[0][1], b3, acc0); MFMA_(ah[1][1], b3, acc1);
        __builtin_amdgcn_s_setprio(0);

        // compare (strict > keeps earliest tile => first-argmin tie semantics)
        #pragma unroll
        for (int r = 0; r < 4; ++r) {
            if (acc0[r] > best[0][r]) { best[0][r] = acc0[r]; bt[0][r] = t; }
            if (acc1[r] > best[1][r]) { best[1][r] = acc1[r]; bt[1][r] = t; }
        }

        __syncthreads();
        cur = (cur == 2) ? 0 : cur + 1;
    }

    // ---- argmax reduce across the 16 lanes holding each row ----
    // C 16x16: col = lane&15 (code), row = (lane>>4)*4 + r
    #pragma unroll
    for (int rt = 0; rt < 2; ++rt)
        #pragma unroll
        for (int r = 0; r < 4; ++r) {
            float b = best[rt][r];
            int bi = bt[rt][r] * 16 + nidx;
            #pragma unroll
            for (int off = 1; off <= 8; off <<= 1) {
                float ob = __shfl_xor(b, off, 64);
                int oi = __shfl_xor(bi, off, 64);
                if (ob > b || (ob == b && oi < bi)) { b = ob; bi = oi; }
            }
            if (nidx == 0)
                idx_lds[wv * 32 + rt * 16 + g * 4 + r] = bi;
        }
    __syncthreads();

    // ---- epilogue: gather fp32 codebook row, write out, loss partial ----
    const int lr = tid >> 1;
    const int grow = block_row0 + lr;
    const int d0 = (tid & 1) * 32;
    const int ci = idx_lds[lr];
    const float invn = inv_lds[lr];
    const float4* xp = (const float4*)(x + (size_t)grow * DIM + d0);
    const float4* qp = (const float4*)(wn + (size_t)ci * DIM + d0);
    float4* op = (float4*)(out_q + (size_t)grow * DIM + d0);
    float ls = 0.f;
    #pragma unroll
    for (int i = 0; i < 8; ++i) {
        float4 qv = qp[i];
        float4 xv4 = xp[i];
        float e0 = qv.x - xv4.x * invn;
        float e1 = qv.y - xv4.y * invn;
        float e2 = qv.z - xv4.z * invn;
        float e3 = qv.w - xv4.w * invn;
        ls += e0 * e0 + e1 * e1 + e2 * e2 + e3 * e3;
        op[i] = qv;
    }
    if (!(tid & 1)) out_idx[grow] = (float)ci;

    float s = ls;
    #pragma unroll
    for (int off = 32; off; off >>= 1) s += __shfl_xor(s, off, 64);
    if (lane == 0) red[wv] = s;
    __syncthreads();
    if (tid == 0) partial[blockIdx.x] = (red[0] + red[1]) + (red[2] + red[3]);
}

__global__ __launch_bounds__(256) void finalize_kernel(
    const float* __restrict__ partial, float* __restrict__ loss_out)
{
    __shared__ float red[4];
    int t = threadIdx.x;
    float s = 0.f;
    #pragma unroll
    for (int i = 0; i < 8; ++i) s += partial[t * 8 + i];  // fixed order
    #pragma unroll
    for (int off = 32; off; off >>= 1) s += __shfl_xor(s, off, 64);
    if ((t & 63) == 0) red[t >> 6] = s;
    __syncthreads();
    if (t == 0)
        *loss_out = 1.25f * (((red[0] + red[1]) + (red[2] + red[3]))
                             / (float)((size_t)N_ROWS * DIM));
}

extern "C" void kernel_launch(void* const* d_in, const int* in_sizes, int n_in,
                              void* d_out, int out_size, void* d_ws, size_t ws_size,
                              hipStream_t stream) {
    const float* x = (const float*)d_in[0];   // [N, D]
    const float* w = (const float*)d_in[1];   // [K, D]
    float* out = (float*)d_out;
    float* ws = (float*)d_ws;

    float* wn      = ws;                                   // 65536 floats
    float* msw     = wn + (size_t)K_CODES * DIM;           // 1024 floats
    float* partial = msw + K_CODES;                        // 2048 floats
    _Float16* wf   = (_Float16*)(partial + 2048);          // 64*2048 halves

    float* out_q    = out;                                 // [N*D]
    float* out_loss = out + (size_t)N_ROWS * DIM;          // [1]
    float* out_idx  = out_loss + 1;                        // [N]

    prep_codebook<<<K_CODES, 64, 0, stream>>>(w, wn, msw, wf);
    vq_main_kernel<<<N_ROWS / ROWS_PER_BLOCK, 256, 0, stream>>>(
        x, wn, msw, wf, out_q, out_idx, partial);
    finalize_kernel<<<1, 256, 0, stream>>>(partial, out_loss);
}

// Round 16
// 130.739 us; speedup vs baseline: 2.0256x; 1.0093x over previous
//
#include <hip/hip_runtime.h>
#include <math.h>

#define N_ROWS 262144
#define DIM 64
#define K_CODES 1024
#define NT 64                 // code tiles of 16
#define ROWS_PER_BLOCK 128
#define EPSF 1e-12f

typedef _Float16 f16x8 __attribute__((ext_vector_type(8)));
typedef float f32x4 __attribute__((ext_vector_type(4)));

// ws layout (floats):
//   wn      : [0, 65536)         normalized codebook fp32 (gather/epilogue)
//   msw     : [65536, 66560)     -0.5 * sum(wn^2) per code
//   partial : [66560, 68608)     per-block loss partials (2048)
//   wf      : halves after that  codebook hi/lo f16, 16x16x32 B-fragment order
//             per 16-code tile t: 2048 halves:
//               [0,512)=hi s0  [512,1024)=hi s1  [1024,1536)=lo s0  [1536,2048)=lo s1
//             within each 512: lane(= g*16 + code%16)*8 + i,  k-dim = s*32+g*8+i

__global__ __launch_bounds__(64) void prep_codebook(
    const float* __restrict__ w, float* __restrict__ wn,
    float* __restrict__ msw, _Float16* __restrict__ wf)
{
    int k = blockIdx.x;
    int d = threadIdx.x;
    float v = w[k * DIM + d];
    float sq = v * v;
    #pragma unroll
    for (int off = 32; off; off >>= 1) sq += __shfl_xor(sq, off, 64);
    float n = fmaxf(sqrtf(sq), EPSF);
    float o = v / n;
    wn[k * DIM + d] = o;
    float s2 = o * o;
    #pragma unroll
    for (int off = 32; off; off >>= 1) s2 += __shfl_xor(s2, off, 64);
    if (d == 0) msw[k] = -0.5f * s2;

    _Float16 hi = (_Float16)o;
    _Float16 lo = (_Float16)(o - (float)hi);
    // B fragment for 16x16x32: lane = g*16 + n holds k-dims s*32 + g*8 + i
    int t = k >> 4, nn = k & 15, s = d >> 5, g = (d >> 3) & 3, i = d & 7;
    size_t base = (size_t)t * 2048 + (size_t)s * 512 + (size_t)(g * 16 + nn) * 8 + i;
    wf[base] = hi;            // h = 0
    wf[base + 1024] = lo;     // h = 1
}

#define MFMA_(A, B, C) C = __builtin_amdgcn_mfma_f32_16x16x32_f16(A, B, C, 0, 0, 0)

__device__ __forceinline__ void load16_to_lds(const void* g, void* l) {
    __builtin_amdgcn_global_load_lds(
        (const __attribute__((address_space(1))) unsigned int*)g,
        (__attribute__((address_space(3))) unsigned int*)l,
        16, 0, 0);
}

// One tile body. Entering body T: buf[CUR] = tile T (resident), buf[(CUR+1)%3]
// = tile T+1 (in flight, 1 body old), buf[NXT=(CUR+2)%3] = free. Issue tile
// T+2 into NXT first, then ds_read + MFMA + compare.
#define BODY(T, CUR, NXT, DO_ISSUE)                                           \
  {                                                                           \
    if (DO_ISSUE) {                                                           \
        load16_to_lds(gnext, &bbuf[(NXT) * 2048 + wv * 512]);                 \
        gnext += 2048;                                                        \
    }                                                                         \
    const _Float16* bp = &bbuf[(CUR) * 2048 + lane * 8];                      \
    f16x8 b0 = *(const f16x8*)(bp);                                           \
    f16x8 b1 = *(const f16x8*)(bp + 512);                                     \
    f16x8 b2 = *(const f16x8*)(bp + 1024);                                    \
    f16x8 b3 = *(const f16x8*)(bp + 1536);                                    \
    float mval = msw_lds[(T) * 16 + nidx];                                    \
    f32x4 acc0 = {mval, mval, mval, mval};                                    \
    f32x4 acc1 = acc0;                                                        \
    __builtin_amdgcn_s_setprio(1);                                            \
    MFMA_(ah[0][0], b0, acc0); MFMA_(ah[1][0], b0, acc1);                     \
    MFMA_(ah[0][1], b1, acc0); MFMA_(ah[1][1], b1, acc1);                     \
    MFMA_(al[0][0], b0, acc0); MFMA_(al[1][0], b0, acc1);                     \
    MFMA_(al[0][1], b1, acc0); MFMA_(al[1][1], b1, acc1);                     \
    MFMA_(ah[0][0], b2, acc0); MFMA_(ah[1][0], b2, acc1);                     \
    MFMA_(ah[0][1], b3, acc0); MFMA_(ah[1][1], b3, acc1);                     \
    __builtin_amdgcn_s_setprio(0);                                            \
    _Pragma("unroll")                                                         \
    for (int r = 0; r < 4; ++r) {                                             \
      if (acc0[r] > best[0][r]) { best[0][r] = acc0[r]; bt[0][r] = (T); }     \
      if (acc1[r] > best[1][r]) { best[1][r] = acc1[r]; bt[1][r] = (T); }     \
    }                                                                         \
  }

__global__ __launch_bounds__(256, 5) void vq_main_kernel(
    const float* __restrict__ x,
    const float* __restrict__ wn,
    const float* __restrict__ msw,
    const _Float16* __restrict__ wf,
    float* __restrict__ out_q,
    float* __restrict__ out_idx,
    float* __restrict__ partial)
{
    __shared__ _Float16 bbuf[3 * 2048];       // triple-buffered 4 KB code tiles
    __shared__ float msw_lds[K_CODES];
    __shared__ int idx_lds[ROWS_PER_BLOCK];
    __shared__ float inv_lds[ROWS_PER_BLOCK];
    __shared__ float red[4];

    const int tid = threadIdx.x;              // 0..255 (4 waves)
    const int wv = tid >> 6;
    const int lane = tid & 63;
    const int nidx = lane & 15;       // code-within-tile / x-row-within-rowtile
    const int g = lane >> 4;          // k-group
    const int block_row0 = blockIdx.x * ROWS_PER_BLOCK;

    // ---- prologue: 32 rows/wave (2 row-tiles of 16), normalize, hi/lo A-frags ----
    // A for 16x16x32: lane = g*16+m holds A[m][k = g*8+i] (+s*32 per kstep)
    f16x8 ah[2][2], al[2][2];
    #pragma unroll
    for (int rt = 0; rt < 2; ++rt) {
        const int arow = block_row0 + wv * 32 + rt * 16 + nidx;
        const float* xrow = x + (size_t)arow * DIM + g * 8;
        float xv[2][8];
        #pragma unroll
        for (int s = 0; s < 2; ++s) {
            float4 q0 = *(const float4*)(xrow + s * 32);
            float4 q1 = *(const float4*)(xrow + s * 32 + 4);
            xv[s][0] = q0.x; xv[s][1] = q0.y; xv[s][2] = q0.z; xv[s][3] = q0.w;
            xv[s][4] = q1.x; xv[s][5] = q1.y; xv[s][6] = q1.z; xv[s][7] = q1.w;
        }
        float ss = 0.f;
        #pragma unroll
        for (int s = 0; s < 2; ++s)
            #pragma unroll
            for (int i = 0; i < 8; ++i) ss += xv[s][i] * xv[s][i];
        ss += __shfl_xor(ss, 16, 64);  // sum across the 4 k-groups of this row
        ss += __shfl_xor(ss, 32, 64);
        float nrm = fmaxf(sqrtf(ss), EPSF);
        float inv = 1.0f / nrm;
        if (g == 0) inv_lds[wv * 32 + rt * 16 + nidx] = inv;
        #pragma unroll
        for (int s = 0; s < 2; ++s)
            #pragma unroll
            for (int i = 0; i < 8; ++i) {
                float v = xv[s][i] * inv;
                _Float16 hi = (_Float16)v;
                ah[rt][s][i] = hi;
                al[rt][s][i] = (_Float16)(v - (float)hi);
            }
    }

    // ---- stage msw into LDS, conflict-free 16B/thread ----
    *(float4*)&msw_lds[tid * 4] = *(const float4*)(msw + tid * 4);

    // ---- issue async loads: tile 0 -> buf0, tile 1 -> buf1 (1 KB per wave) ----
    const _Float16* gnext = wf + (size_t)wv * 512 + (size_t)lane * 8;
    load16_to_lds(gnext,        &bbuf[wv * 512]);
    load16_to_lds(gnext + 2048, &bbuf[2048 + wv * 512]);
    gnext += 2 * 2048;                        // next issue target: tile 2
    __syncthreads();                          // full drain once: tiles 0,1 resident

    float best[2][4];
    int bt[2][4];
    #pragma unroll
    for (int rt = 0; rt < 2; ++rt)
        #pragma unroll
        for (int r = 0; r < 4; ++r) { best[rt][r] = -3.4e38f; bt[rt][r] = 0; }

    // ---- main loop: counted-vmcnt discipline (T4) ----
    // At end of body t, per-wave outstanding gload_lds (FIFO): {t+1, t+2}.
    // vmcnt(1) retires t+1 (needed next body) and leaves t+2 IN FLIGHT across
    // the barrier — never drain to 0 in the main loop.
    int cur = 0;
    for (int t = 0; t < NT - 2; ++t) {
        int nxt = cur - 1; if (nxt < 0) nxt = 2;    // (cur+2) mod 3
        BODY(t, cur, nxt, true)
        asm volatile("s_waitcnt vmcnt(1)");
        __builtin_amdgcn_s_barrier();
        cur = (cur == 2) ? 0 : cur + 1;
    }
    // body NT-2 (cur = 62 % 3 = 2): no issue; drain fully for the last tile
    BODY(NT - 2, 2, 0, false)
    asm volatile("s_waitcnt vmcnt(0)");
    __builtin_amdgcn_s_barrier();
    // body NT-1 (cur = 63 % 3 = 0): no issue, no barrier
    BODY(NT - 1, 0, 0, false)

    // ---- argmax reduce across the 16 lanes holding each row ----
    // C 16x16: col = lane&15 (code), row = (lane>>4)*4 + r
    #pragma unroll
    for (int rt = 0; rt < 2; ++rt)
        #pragma unroll
        for (int r = 0; r < 4; ++r) {
            float b = best[rt][r];
            int bi = bt[rt][r] * 16 + nidx;
            #pragma unroll
            for (int off = 1; off <= 8; off <<= 1) {
                float ob = __shfl_xor(b, off, 64);
                int oi = __shfl_xor(bi, off, 64);
                if (ob > b || (ob == b && oi < bi)) { b = ob; bi = oi; }
            }
            if (nidx == 0)
                idx_lds[wv * 32 + rt * 16 + g * 4 + r] = bi;
        }
    __syncthreads();

    // ---- epilogue: gather fp32 codebook row, write out, loss partial ----
    const int lr = tid >> 1;
    const int grow = block_row0 + lr;
    const int d0 = (tid & 1) * 32;
    const int ci = idx_lds[lr];
    const float invn = inv_lds[lr];
    const float4* xp = (const float4*)(x + (size_t)grow * DIM + d0);
    const float4* qp = (const float4*)(wn + (size_t)ci * DIM + d0);
    float4* op = (float4*)(out_q + (size_t)grow * DIM + d0);
    float ls = 0.f;
    #pragma unroll
    for (int i = 0; i < 8; ++i) {
        float4 qv = qp[i];
        float4 xv4 = xp[i];
        float e0 = qv.x - xv4.x * invn;
        float e1 = qv.y - xv4.y * invn;
        float e2 = qv.z - xv4.z * invn;
        float e3 = qv.w - xv4.w * invn;
        ls += e0 * e0 + e1 * e1 + e2 * e2 + e3 * e3;
        op[i] = qv;
    }
    if (!(tid & 1)) out_idx[grow] = (float)ci;

    float s = ls;
    #pragma unroll
    for (int off = 32; off; off >>= 1) s += __shfl_xor(s, off, 64);
    if (lane == 0) red[wv] = s;
    __syncthreads();
    if (tid == 0) partial[blockIdx.x] = (red[0] + red[1]) + (red[2] + red[3]);
}

__global__ __launch_bounds__(256) void finalize_kernel(
    const float* __restrict__ partial, float* __restrict__ loss_out)
{
    __shared__ float red[4];
    int t = threadIdx.x;
    float s = 0.f;
    #pragma unroll
    for (int i = 0; i < 8; ++i) s += partial[t * 8 + i];  // fixed order
    #pragma unroll
    for (int off = 32; off; off >>= 1) s += __shfl_xor(s, off, 64);
    if ((t & 63) == 0) red[t >> 6] = s;
    __syncthreads();
    if (t == 0)
        *loss_out = 1.25f * (((red[0] + red[1]) + (red[2] + red[3]))
                             / (float)((size_t)N_ROWS * DIM));
}

extern "C" void kernel_launch(void* const* d_in, const int* in_sizes, int n_in,
                              void* d_out, int out_size, void* d_ws, size_t ws_size,
                              hipStream_t stream) {
    const float* x = (const float*)d_in[0];   // [N, D]
    const float* w = (const float*)d_in[1];   // [K, D]
    float* out = (float*)d_out;
    float* ws = (float*)d_ws;

    float* wn      = ws;                                   // 65536 floats
    float* msw     = wn + (size_t)K_CODES * DIM;           // 1024 floats
    float* partial = msw + K_CODES;                        // 2048 floats
    _Float16* wf   = (_Float16*)(partial + 2048);          // 64*2048 halves

    float* out_q    = out;                                 // [N*D]
    float* out_loss = out + (size_t)N_ROWS * DIM;          // [1]
    float* out_idx  = out_loss + 1;                        // [N]

    prep_codebook<<<K_CODES, 64, 0, stream>>>(w, wn, msw, wf);
    vq_main_kernel<<<N_ROWS / ROWS_PER_BLOCK, 256, 0, stream>>>(
        x, wn, msw, wf, out_q, out_idx, partial);
    finalize_kernel<<<1, 256, 0, stream>>>(partial, out_loss);
}